// Round 2
// baseline (62.965 us; speedup 1.0000x reference)
//
#include <hip/hip_runtime.h>

typedef float  f32x4 __attribute__((ext_vector_type(4)));
typedef float  f32x2 __attribute__((ext_vector_type(2)));
typedef short  s16x8 __attribute__((ext_vector_type(8)));

// fp32 -> bf16 round-to-nearest-even
__device__ __forceinline__ unsigned int f2bf(float x) {
    unsigned int u = __float_as_uint(x);
    return (u + 0x7FFFu + ((u >> 16) & 1u)) >> 16;
}

// XOR-swizzled element offset within a [64 rows][64 t] bf16 plane (128B rows).
__device__ __forceinline__ int swz(int row, int t) {
    int g = ((row ^ (row >> 3)) & 7) << 3;
    return row * 64 + (t ^ g);
}

__global__ __launch_bounds__(256, 5)
void upsample_mfma_kernel(const float* __restrict__ yt,
                          const float* __restrict__ Ht,
                          const float* __restrict__ biases,
                          float* __restrict__ out)
{
    // [px'][row][t] bf16 planes, 8KB each -> 32KB total => 5 WG/CU
    __shared__ __align__(16) unsigned short Wl[2][4096];  // row = uu
    __shared__ __align__(16) unsigned short Al[2][4096];  // row = b

    // XCD-aware bijective swizzle: 2048 WGs -> chunks of 256 per XCD so the
    // WGs sharing yt/Ht cachelines (same py, adjacent pxp) share an L2.
    const int wg  = blockIdx.x;
    const int nw  = (wg & 7) * 256 + (wg >> 3);
    const int py  = nw >> 5;    // 0..63
    const int pxp = nw & 31;    // px pair: px = pxp*2 + {0,1}
    const int tid = threadIdx.x;

    // ---- stage W tile: Ht[t, py*8+uy, pxp*16 + 0..15] -> Wl[px'][uu][t] ----
    {
        const int c4  = tid & 3;          // 16B col group
        const int uy  = (tid >> 2) & 7;
        const int t4l = tid >> 5;         // 0..7
        const float* base = Ht + (py * 8 + uy) * 512 + pxp * 16 + c4 * 4;
        #pragma unroll
        for (int pass = 0; pass < 2; ++pass) {
            const int tt4 = pass * 8 + t4l;           // t-base = tt4*4
            f32x4 v0 = *(const f32x4*)(base + (tt4 * 4 + 0) * 262144);
            f32x4 v1 = *(const f32x4*)(base + (tt4 * 4 + 1) * 262144);
            f32x4 v2 = *(const f32x4*)(base + (tt4 * 4 + 2) * 262144);
            f32x4 v3 = *(const f32x4*)(base + (tt4 * 4 + 3) * 262144);
            #pragma unroll
            for (int cc = 0; cc < 4; ++cc) {
                const int c   = c4 * 4 + cc;          // 0..15
                const int pxl = c >> 3;
                const int uu  = uy * 8 + (c & 7);
                unsigned int lo = f2bf(v0[cc]) | (f2bf(v1[cc]) << 16);
                unsigned int hi = f2bf(v2[cc]) | (f2bf(v3[cc]) << 16);
                *(uint2*)&Wl[pxl][swz(uu, tt4 * 4)] = make_uint2(lo, hi);
            }
        }
    }

    // ---- stage A tile: yt[b, t, py, pxp*2 + 0..1] -> Al[px'][b][t] ----
    {
        const int t4 = tid & 15;
        const int bl = tid >> 4;          // 0..15
        #pragma unroll
        for (int pass = 0; pass < 4; ++pass) {
            const int b = pass * 16 + bl; // 0..63
            const float* base = yt + b * 262144 + py * 64 + pxp * 2;
            f32x2 v0 = *(const f32x2*)(base + (t4 * 4 + 0) * 4096);
            f32x2 v1 = *(const f32x2*)(base + (t4 * 4 + 1) * 4096);
            f32x2 v2 = *(const f32x2*)(base + (t4 * 4 + 2) * 4096);
            f32x2 v3 = *(const f32x2*)(base + (t4 * 4 + 3) * 4096);
            #pragma unroll
            for (int pp = 0; pp < 2; ++pp) {
                unsigned int lo = f2bf(v0[pp]) | (f2bf(v1[pp]) << 16);
                unsigned int hi = f2bf(v2[pp]) | (f2bf(v3[pp]) << 16);
                *(uint2*)&Al[pp][swz(b, t4 * 4)] = make_uint2(lo, hi);
            }
        }
    }

    __syncthreads();

    // ---- per-wave 32x64x64 GEMM: two waves per px split the B dim ----
    const int w    = tid >> 6;        // wave 0..3
    const int pxl  = w >> 1;          // px' 0..1
    const int half = w & 1;           // b-half
    const int l = tid & 63;
    const int r = l & 15;
    const int q = l >> 4;
    const int px = pxp * 2 + pxl;
    const int p  = py * 64 + px;

    f32x4 acc[2][4];
    #pragma unroll
    for (int nb = 0; nb < 4; ++nb) {
        const float bv = biases[p * 64 + nb * 16 + r];
        acc[0][nb] = (f32x4){bv, bv, bv, bv};
        acc[1][nb] = (f32x4){bv, bv, bv, bv};
    }

    #pragma unroll
    for (int ks = 0; ks < 2; ++ks) {
        const int t = ks * 32 + q * 8;     // k = q*8 + j
        s16x8 af[2], bfv[4];
        #pragma unroll
        for (int mb = 0; mb < 2; ++mb)
            af[mb] = *(const s16x8*)&Al[pxl][swz(half * 32 + mb * 16 + r, t)];
        #pragma unroll
        for (int nb = 0; nb < 4; ++nb)
            bfv[nb] = *(const s16x8*)&Wl[pxl][swz(nb * 16 + r, t)];
        #pragma unroll
        for (int mb = 0; mb < 2; ++mb)
            #pragma unroll
            for (int nb = 0; nb < 4; ++nb)
                acc[mb][nb] = __builtin_amdgcn_mfma_f32_16x16x32_bf16(
                    af[mb], bfv[nb], acc[mb][nb], 0, 0, 0);
    }

    // ---- epilogue: pixel-shuffle store ----
    #pragma unroll
    for (int mb = 0; mb < 2; ++mb) {
        #pragma unroll
        for (int nb = 0; nb < 4; ++nb) {
            const int n   = nb * 16 + r;          // uu
            const int row = py * 8 + (n >> 3);
            const int col = px * 8 + (n & 7);
            #pragma unroll
            for (int i = 0; i < 4; ++i) {
                const int b = half * 32 + mb * 16 + q * 4 + i;
                out[(b * 512 + row) * 512 + col] = acc[mb][nb][i];
            }
        }
    }
}

extern "C" void kernel_launch(void* const* d_in, const int* in_sizes, int n_in,
                              void* d_out, int out_size, void* d_ws, size_t ws_size,
                              hipStream_t stream) {
    const float* yt     = (const float*)d_in[0];
    const float* Ht     = (const float*)d_in[1];
    const float* biases = (const float*)d_in[2];
    float* out          = (float*)d_out;
    upsample_mfma_kernel<<<dim3(2048), dim3(256), 0, stream>>>(yt, Ht, biases, out);
}

// Round 3
// 40.567 us; speedup vs baseline: 1.5521x; 1.5521x over previous
//
#include <hip/hip_runtime.h>

typedef float f32x4 __attribute__((ext_vector_type(4)));
typedef short s16x8 __attribute__((ext_vector_type(8)));
typedef unsigned int u32;

// fp32 -> bf16 round-to-nearest-even
__device__ __forceinline__ u32 f2bf(float x) {
    u32 u = __float_as_uint(x);
    return (u + 0x7FFFu + ((u >> 16) & 1u)) >> 16;
}
__device__ __forceinline__ u32 pk(float a, float b) {
    return f2bf(a) | (f2bf(b) << 16);
}

// WG = (py, 16-px quarter, 32-b half). K-loop over 4 t-tiles of 16.
// LDS rows padded to 24 elems (48B) + 8-elem plane pad -> conflict-light
// without XOR swizzles (row stride 12 banks, plane stride 4 banks).
__global__ __launch_bounds__(256, 2)
void upsample_mfma_kernel(const float* __restrict__ yt,
                          const float* __restrict__ Ht,
                          const float* __restrict__ biases,
                          float* __restrict__ out)
{
    __shared__ __align__(16) unsigned short Al[16 * 776];   // [px][b:32][t:24]
    __shared__ __align__(16) unsigned short Wl[16 * 1544];  // [px][uu:64][t:24]

    const int wg = blockIdx.x;
    // XCD swizzle: chunks of 64 -> 8 py rows per XCD; bh pairs (shared Ht)
    // and pxq pairs (shared yt lines) stay on one XCD.
    const int nw  = (wg & 7) * 64 + (wg >> 3);
    const int py  = nw >> 3;
    const int pxq = (nw >> 1) & 3;
    const int bh  = nw & 1;
    const int px0 = pxq * 16;
    const int b0  = bh * 32;
    const int tid = (int)threadIdx.x;

    // ---- staging coords ----
    const int a_pxg = tid & 3;            // 4 px per f32x4
    const int a_bb  = (tid >> 2) & 31;    // b
    const int a_tg  = tid >> 7;           // which 8-t half
    const float* a_base = yt + (size_t)(b0 + a_bb) * 262144 + py * 64 + px0 + a_pxg * 4;

    const int w_cc = tid & 31;            // 16B c-chunk; 32 lanes = 512B contiguous
    const int w_uy = tid >> 5;            // 0..7
    const float* w_base = Ht + (size_t)(py * 8 + w_uy) * 512 + pxq * 128 + w_cc * 4;
    const int w_px  = w_cc >> 1;
    const int w_uu0 = w_uy * 8 + (w_cc & 1) * 4;

    // ---- compute coords ----
    const int wv = tid >> 6;              // wave; owns px_local wv*4..wv*4+3
    const int l  = tid & 63;
    const int r  = l & 15;
    const int q  = l >> 4;
    const bool qlo = (q < 2);             // K=16 effective: zero q>=2 frags
    const int qq = (q & 1) * 8;

    f32x4 acc[4][2][4];                   // [pxi][mb][nb]
    #pragma unroll
    for (int pxi = 0; pxi < 4; ++pxi) {
        const int p = py * 64 + px0 + wv * 4 + pxi;
        #pragma unroll
        for (int nb = 0; nb < 4; ++nb) {
            const float bv = biases[p * 64 + nb * 16 + r];
            #pragma unroll
            for (int mb = 0; mb < 2; ++mb)
                acc[pxi][mb][nb] = (f32x4){bv, bv, bv, bv};
        }
    }

    const s16x8 zz = (s16x8){0, 0, 0, 0, 0, 0, 0, 0};

    #pragma unroll
    for (int tt = 0; tt < 4; ++tt) {
        const int t0 = tt * 16;
        if (tt) __syncthreads();          // prev compute done before overwrite

        // ---- stage A: yt[b, t0..t0+15, py, px0..px0+15] ----
        {
            f32x4 v[8];
            #pragma unroll
            for (int j = 0; j < 8; ++j)
                v[j] = *(const f32x4*)(a_base + (size_t)(t0 + a_tg * 8 + j) * 4096);
            #pragma unroll
            for (int i = 0; i < 4; ++i) {
                uint4 g;
                g.x = pk(v[0][i], v[1][i]);
                g.y = pk(v[2][i], v[3][i]);
                g.z = pk(v[4][i], v[5][i]);
                g.w = pk(v[6][i], v[7][i]);
                *(uint4*)&Al[(a_pxg * 4 + i) * 776 + a_bb * 24 + a_tg * 8] = g;
            }
        }
        // ---- stage W: Ht[t0..t0+15, py*8+uy, pxq*128 + 0..127] ----
        #pragma unroll
        for (int h = 0; h < 2; ++h) {
            f32x4 v[8];
            #pragma unroll
            for (int j = 0; j < 8; ++j)
                v[j] = *(const f32x4*)(w_base + (size_t)(t0 + h * 8 + j) * 262144);
            #pragma unroll
            for (int i = 0; i < 4; ++i) {
                uint4 g;
                g.x = pk(v[0][i], v[1][i]);
                g.y = pk(v[2][i], v[3][i]);
                g.z = pk(v[4][i], v[5][i]);
                g.w = pk(v[6][i], v[7][i]);
                *(uint4*)&Wl[w_px * 1544 + (w_uu0 + i) * 24 + h * 8] = g;
            }
        }
        __syncthreads();

        // ---- compute: per px, [32b x 16t] x [16t x 64uu] ----
        #pragma unroll
        for (int pxi = 0; pxi < 4; ++pxi) {
            const unsigned short* ap = &Al[(wv * 4 + pxi) * 776];
            const unsigned short* wp = &Wl[(wv * 4 + pxi) * 1544];
            s16x8 af[2], bfr[4];
            #pragma unroll
            for (int mb = 0; mb < 2; ++mb)
                af[mb] = qlo ? *(const s16x8*)&ap[(mb * 16 + r) * 24 + qq] : zz;
            #pragma unroll
            for (int nb = 0; nb < 4; ++nb)
                bfr[nb] = qlo ? *(const s16x8*)&wp[(nb * 16 + r) * 24 + qq] : zz;
            #pragma unroll
            for (int mb = 0; mb < 2; ++mb)
                #pragma unroll
                for (int nb = 0; nb < 4; ++nb)
                    acc[pxi][mb][nb] = __builtin_amdgcn_mfma_f32_16x16x32_bf16(
                        af[mb], bfr[nb], acc[pxi][mb][nb], 0, 0, 0);
        }
    }

    // ---- epilogue: pixel-shuffle store ----
    #pragma unroll
    for (int pxi = 0; pxi < 4; ++pxi) {
        const int px = px0 + wv * 4 + pxi;
        #pragma unroll
        for (int mb = 0; mb < 2; ++mb) {
            #pragma unroll
            for (int nb = 0; nb < 4; ++nb) {
                const int n   = nb * 16 + r;
                const int row = py * 8 + (n >> 3);
                const int col = px * 8 + (n & 7);
                #pragma unroll
                for (int i = 0; i < 4; ++i) {
                    const int b = b0 + mb * 16 + q * 4 + i;
                    out[(size_t)(b * 512 + row) * 512 + col] = acc[pxi][mb][nb][i];
                }
            }
        }
    }
}

extern "C" void kernel_launch(void* const* d_in, const int* in_sizes, int n_in,
                              void* d_out, int out_size, void* d_ws, size_t ws_size,
                              hipStream_t stream) {
    const float* yt     = (const float*)d_in[0];
    const float* Ht     = (const float*)d_in[1];
    const float* biases = (const float*)d_in[2];
    float* out          = (float*)d_out;
    upsample_mfma_kernel<<<dim3(512), dim3(256), 0, stream>>>(yt, Ht, biases, out);
}